// Round 1
// baseline (59681.464 us; speedup 1.0000x reference)
//
#include <hip/hip_runtime.h>
#include <hip/hip_fp16.h>
#include <math.h>

// EarthMoverDistance: exact Hungarian (JV successive shortest path).
// B=8, N=1024, 3-D Euclidean cost. One wave per batch; lane owns 16 columns
// (c = lane*16+k) in registers.
// R7 (base = R6): add the two missing JV phases ahead of SSP:
//  - REDUCTION TRANSFER: rows matched by exactly one column get
//    v[j1] -= (min reduced cost excl. j1), u[i] = that min. Tightens duals.
//  - AUGMENTING ROW REDUCTION (2 passes; strict-case displaced row is
//    re-processed immediately like JV's free[--k], tie-case deferred to the
//    next pass): resolves most free rows at ~one row-scan each and raises
//    the dual objective so remaining SSP searches settle few columns.
//  Both phases only decrease v / set u invariant-preserving (c-u-v >= 0,
//  equality on matched edges), so SSP remains exact; SSP also catches any
//  row the capped ARR leaves free (fp16 tie chains are bounded by ARR_CAP).
//  - SSP local argmin: depth-16 select chain -> depth-4 tournament
//    (NaN settled slots pre-masked to INF), shortening the per-settle
//    dependent chain.
// fp16 cost matrix in d_ws (2 MB/batch -> XCD-L2 resident). SSP/ARR exact
// on the rounded matrix; FINAL SUM recomputed in fp32 from coords.
// Deferred dual updates (validated rounds 1-6, absmax 0.0).

#define N     1024
#define BATCH 8
#define NSLOT 16          // columns per lane
#define INFV  1e9f
#define QN    2048        // ARR worklist capacity
#define ARR_CAP (6 * N)   // global ARR iteration cap (SSP catches leftovers)

__global__ void emd_zero_kernel(float* out) { out[0] = 0.0f; }

// ---- cost cache: D[b][r][c] = fp16(dist(S1[b][r], S2[b][c])) ----
__global__ __launch_bounds__(256)
void emd_dist_kernel(const float* __restrict__ S1, const float* __restrict__ S2,
                     __half* __restrict__ D) {
    int b = blockIdx.x >> 10;
    int r = blockIdx.x & (N - 1);
    const float* s1 = S1 + ((size_t)b * N + r) * 3;
    float x1 = s1[0], y1 = s1[1], z1 = s1[2];
    const float* s2 = S2 + (size_t)b * N * 3;
    __half* drow = D + ((size_t)b * N + r) * (size_t)N;
    for (int c = threadIdx.x; c < N; c += 256) {
        float dx = x1 - s2[3 * c], dy = y1 - s2[3 * c + 1], dz = z1 - s2[3 * c + 2];
        drow[c] = __float2half_rn(sqrtf(dx * dx + dy * dy + dz * dz));
    }
}

// ---- column reduction over the fp16 matrix: v[c] = min_r C'(r,c) ----
__global__ __launch_bounds__(256)
void emd_colmin_kernel(const __half* __restrict__ D, float* __restrict__ V,
                       int* __restrict__ I) {
    int b = blockIdx.x >> 2;
    int c = ((blockIdx.x & 3) << 8) + threadIdx.x;
    const __half* Db = D + ((size_t)b << 20);
    float best = INFV; int bi = 1;
    for (int r = 0; r < N; ++r) {
        float d = __half2float(Db[(size_t)r * N + c]);
        if (d < best) { best = d; bi = r + 1; }
    }
    V[b * N + c] = best;
    I[b * N + c] = bi;
}

template<int CTRL>
__device__ __forceinline__ float dppmin(float x) {
    int xi = __float_as_int(x);
    int yi = __builtin_amdgcn_update_dpp(xi, xi, CTRL, 0xF, 0xF, false);
    return fminf(x, __int_as_float(yi));
}

__device__ __forceinline__ float wave_min_f32(float x) {
    x = dppmin<0x111>(x);   // row_shr:1
    x = dppmin<0x112>(x);   // row_shr:2
    x = dppmin<0x114>(x);   // row_shr:4
    x = dppmin<0x118>(x);   // row_shr:8
    x = dppmin<0x142>(x);   // row_bcast:15
    x = dppmin<0x143>(x);   // row_bcast:31 -> lane 63 has global min
    return __int_as_float(__builtin_amdgcn_readlane(__float_as_int(x), 63));
}

struct Frag { uint4 w0, w1; float ur; float4 q; };

template<bool CACHED>
__global__ __launch_bounds__(64, 1)
void emd_jv_kernel(const float* __restrict__ S1,
                   const float* __restrict__ S2,
                   const __half* __restrict__ Dc,
                   const float* __restrict__ Vin,
                   const int*   __restrict__ Iin,
                   float* __restrict__ out) {
    __shared__ float4 s1u[N + 1];     // row coords (final fp32 sum)
    __shared__ float  u_lds[N + 1];   // row potentials
    __shared__ float  dentry[N + 1];  // D value when column settled
    __shared__ int    rowm[N + 1];    // row -> matched col (0 = free)
    __shared__ int    cnt[N + 1];     // # columns whose argmin row is r
    __shared__ int    qbuf[QN];       // ARR free-row worklist

    const int lane = threadIdx.x;
    const int b = blockIdx.x;
    const float* s1g = S1 + (size_t)b * N * 3;
    const float* s2g = S2 + (size_t)b * N * 3;
    const __half* Db = CACHED ? (Dc + ((size_t)b << 20)) : (const __half*)0;
    const float NANF = __int_as_float(0x7fc00000);

    for (int t = lane; t < N; t += 64) {
        s1u[t + 1] = make_float4(s1g[3 * t], s1g[3 * t + 1], s1g[3 * t + 2], 0.0f);
        u_lds[t + 1] = 0.0f;
        rowm[t + 1] = 0;
        cnt[t + 1] = 0;
    }
    if (lane == 0) { u_lds[0] = 0.0f; rowm[0] = 0; cnt[0] = 0; }

    // ---- per-lane column state: col j = c+1, c = lane*16+k ----
    float v[NSLOT];       // column potentials
    int   pr[NSLOT];      // matched row (0 = free)
    int   jpk[NSLOT];     // packed (pr<<11)|j
    int   imin[NSLOT];
    float x2[NSLOT], y2[NSLOT], z2[NSLOT];  // S2 coords (final fp32 sum)

#pragma unroll
    for (int k = 0; k < NSLOT; ++k) {
        int pt = lane * NSLOT + k;
        x2[k] = s2g[3 * pt + 0];
        y2[k] = s2g[3 * pt + 1];
        z2[k] = s2g[3 * pt + 2];
    }
    if (CACHED) {
#pragma unroll
        for (int k = 0; k < NSLOT; ++k) {
            int c = lane * NSLOT + k;
            v[k] = Vin[b * N + c];
            imin[k] = Iin[b * N + c];
        }
    } else {
#pragma unroll
        for (int k = 0; k < NSLOT; ++k) { v[k] = INFV; imin[k] = 1; }
    }
    __syncthreads();

    if (!CACHED) {
        for (int r = 1; r <= N; ++r) {
            float4 qq = s1u[r];
#pragma unroll
            for (int k = 0; k < NSLOT; ++k) {
                float dx = qq.x - x2[k], dy = qq.y - y2[k], dz = qq.z - z2[k];
                float d2 = dx * dx + dy * dy + dz * dz;
                bool upd = d2 < v[k];
                v[k] = upd ? d2 : v[k];
                imin[k] = upd ? r : imin[k];
            }
        }
#pragma unroll
        for (int k = 0; k < NSLOT; ++k) v[k] = sqrtf(v[k]);
    }

    // ---- greedy matching on tight edges (+ match counts for RT) ----
#pragma unroll
    for (int k = 0; k < NSLOT; ++k) {
        int j = lane * NSLOT + k + 1;
        int r = imin[k];
        atomicAdd(&cnt[r], 1);
        int old = atomicCAS(&rowm[r], 0, j);
        pr[k] = (old == 0) ? r : 0;
        jpk[k] = (pr[k] << 11) | j;
    }
    __syncthreads();

    float minv[NSLOT];
    int   way[NSLOT];

    // issue row-r loads (cost-row fragment + u[r]); consumer waits only these
    auto issueLoads = [&](int rr) -> Frag {
        Frag F;
        if (CACHED) {
            const uint4* dr = (const uint4*)(Db + (size_t)(rr - 1) * N);
            F.w0 = dr[lane * 2 + 0];       // 8 halves
            F.w1 = dr[lane * 2 + 1];       // 8 halves
        } else {
            F.q = s1u[rr];
        }
        F.ur = u_lds[rr];
        return F;
    };

    auto applyFrag = [&](const Frag& F, int jpred, float Dh) {
        float base = Dh - F.ur;
        if (CACHED) {
            float h[NSLOT];
            const unsigned* w = (const unsigned*)&F.w0;   // w0,w1 contiguous
#pragma unroll
            for (int t = 0; t < 8; ++t) {
                unsigned word = w[t];
                __half2 hh = *reinterpret_cast<const __half2*>(&word);
                float2 f2 = __half22float2(hh);
                h[2 * t] = f2.x; h[2 * t + 1] = f2.y;
            }
#pragma unroll
            for (int k = 0; k < NSLOT; ++k) {
                float cur = (h[k] - v[k]) + base;
                bool upd = cur < minv[k];         // false for NaN (settled)
                minv[k] = upd ? cur : minv[k];
                way[k] = upd ? jpred : way[k];
            }
        } else {
#pragma unroll
            for (int k = 0; k < NSLOT; ++k) {
                float dx = F.q.x - x2[k], dy = F.q.y - y2[k], dz = F.q.z - z2[k];
                float d = sqrtf(dx * dx + dy * dy + dz * dz);
                float cur = (d - v[k]) + base;
                bool upd = cur < minv[k];
                minv[k] = upd ? cur : minv[k];
                way[k] = upd ? jpred : way[k];
            }
        }
    };

    // reduced-cost row: red[k] = C'(rr, col_k) - v[col_k]   (no u term)
    auto rowRed = [&](int rr, float (&red)[NSLOT]) {
        if (CACHED) {
            const uint4* dr = (const uint4*)(Db + (size_t)(rr - 1) * N);
            uint4 w0 = dr[lane * 2 + 0];
            uint4 w1 = dr[lane * 2 + 1];
            unsigned wb[8] = { w0.x, w0.y, w0.z, w0.w, w1.x, w1.y, w1.z, w1.w };
#pragma unroll
            for (int t = 0; t < 8; ++t) {
                __half2 hh = *reinterpret_cast<const __half2*>(&wb[t]);
                float2 f2 = __half22float2(hh);
                red[2 * t]     = f2.x - v[2 * t];
                red[2 * t + 1] = f2.y - v[2 * t + 1];
            }
        } else {
            float4 qq = s1u[rr];
#pragma unroll
            for (int k = 0; k < NSLOT; ++k) {
                float dx = qq.x - x2[k], dy = qq.y - y2[k], dz = qq.z - z2[k];
                red[k] = sqrtf(dx * dx + dy * dy + dz * dz) - v[k];
            }
        }
    };

    auto colRowOf = [&](int j) -> int {       // colsol[j] via register pr
        int cc = j - 1, lo = cc >> 4, kk = cc & 15;
        int ploc = pr[0];
#pragma unroll
        for (int k = 1; k < NSLOT; ++k) if (k == kk) ploc = pr[k];
        return __builtin_amdgcn_readlane(ploc, lo);
    };
    auto assignCol = [&](int j, int row) {    // colsol[j] = row
        int cc = j - 1, lo = cc >> 4, kk = cc & 15;
        bool mine = (lane == lo);
#pragma unroll
        for (int k = 0; k < NSLOT; ++k)
            if (k == kk && mine) { pr[k] = row; jpk[k] = (row << 11) | j; }
    };
    auto addV = [&](int j, float d) {         // v[j] += d
        int cc = j - 1, lo = cc >> 4, kk = cc & 15;
        bool mine = (lane == lo);
#pragma unroll
        for (int k = 0; k < NSLOT; ++k)
            if (k == kk && mine) v[k] += d;
    };

    // ---- REDUCTION TRANSFER (rows matched by exactly one column) ----
    for (int i = 1; i <= N; ++i) {
        int j1 = rowm[i];
        if (j1 == 0 || cnt[i] != 1) continue;
        float red[NSLOT];
        rowRed(i, red);
        {   // mask out the matched column
            int cc = j1 - 1, lo = cc >> 4, kk = cc & 15;
            bool mine = (lane == lo);
#pragma unroll
            for (int k = 0; k < NSLOT; ++k)
                if (k == kk && mine) red[k] = INFV;
        }
        float tv[NSLOT];
#pragma unroll
        for (int k = 0; k < NSLOT; ++k) tv[k] = red[k];
#pragma unroll
        for (int s = 1; s < NSLOT; s <<= 1) {
#pragma unroll
            for (int k = 0; k < NSLOT; k += 2 * s)
                tv[k] = fminf(tv[k], tv[k + s]);
        }
        float m = wave_min_f32(tv[0]);
        if (m > 0.0f) {
            addV(j1, -m);
            if (lane == 0) u_lds[i] = m;
        }
    }
    __syncthreads();

    // ---- build free-row worklist (deterministic order) ----
    int tail = 0;
    for (int b0 = 1; b0 <= N; b0 += 64) {
        int i = b0 + lane;
        bool fr = (i <= N) && (rowm[i] == 0);
        unsigned long long mb = __ballot(fr);
        int pre = __popcll(mb & ((1ull << lane) - 1ull));
        if (fr) qbuf[tail + pre] = i;
        tail += (int)__popcll(mb);
    }

    // ---- AUGMENTING ROW REDUCTION (2 passes, JV-style) ----
    {
        int head = 0, pending = 0, iter = 0;
        for (int pass = 0; pass < 2; ++pass) {
            int pend = tail;
            while ((head < pend || pending) && ++iter <= ARR_CAP) {
                int i;
                if (pending) { i = pending; pending = 0; }
                else i = qbuf[head++];

                float red[NSLOT];
                rowRed(i, red);
                // local (min, secondmin, argmin-col)
                float m1 = INFV, m2 = INFV; int c1 = 0;
#pragma unroll
                for (int k = 0; k < NSLOT; ++k) {
                    float val = red[k];
                    bool t1 = val < m1, t2 = val < m2;
                    m2 = t1 ? m1 : (t2 ? val : m2);
                    c1 = t1 ? (lane * NSLOT + k + 1) : c1;
                    m1 = t1 ? val : m1;
                }
                // wave all-reduce of (m1, m2, c1), lowest-col tiebreak
#pragma unroll
                for (int off = 32; off >= 1; off >>= 1) {
                    float om1 = __shfl_xor(m1, off);
                    float om2 = __shfl_xor(m2, off);
                    int   oc1 = __shfl_xor(c1, off);
                    float hi = fmaxf(m1, om1);
                    m2 = fminf(fminf(m2, om2), hi);
                    bool tk = (om1 < m1) || ((om1 == m1) && (oc1 < c1));
                    m1 = tk ? om1 : m1;
                    c1 = tk ? oc1 : c1;
                }
                int j1 = c1;
                bool strict = m1 < m2;
                int i0 = colRowOf(j1);
                bool doassign = true;
                if (strict) {
                    addV(j1, -(m2 - m1));      // j1's reduced cost -> m2
                } else if (i0 != 0) {
                    // tie & j1 occupied: pick another tie column
                    unsigned msk = 0u;
#pragma unroll
                    for (int k = 0; k < NSLOT; ++k)
                        msk |= (red[k] == m1) ? (1u << k) : 0u;
                    if (lane == ((j1 - 1) >> 4)) msk &= ~(1u << ((j1 - 1) & 15));
                    unsigned long long lm = __ballot(msk != 0u);
                    if (lm != 0ull) {
                        int l = __ffsll((long long)lm) - 1;
                        unsigned mk = (unsigned)__builtin_amdgcn_readlane((int)msk, l);
                        int k2 = __ffs((int)mk) - 1;
                        j1 = l * NSLOT + k2 + 1;
                        i0 = colRowOf(j1);
                    } else {
                        doassign = false;       // defensive: row stays free
                    }
                }
                if (doassign) {
                    assignCol(j1, i);
                    if (lane == 0) {
                        rowm[i] = j1;
                        u_lds[i] = strict ? m2 : m1;
                        if (i0 != 0) rowm[i0] = 0;
                    }
                    if (i0 != 0) {
                        if (strict) pending = i0;            // JV free[--k]
                        else if (tail < QN) qbuf[tail++] = i0; // next pass
                    }
                }
            }
            if (iter > ARR_CAP) break;
            head = pend;
        }
    }
    __syncthreads();

    // ---- successive shortest paths for remaining free rows (exact on C') ----
    for (int i = 1; i <= N; ++i) {
        if (rowm[i] != 0) continue;

        unsigned used = 0u;
        float DT = 0.0f;
        int freecol = 0;

        Frag F0 = issueLoads(i);          // overlaps minv/way init
#pragma unroll
        for (int k = 0; k < NSLOT; ++k) { minv[k] = INFV; way[k] = 0; }
        applyFrag(F0, 0, 0.0f);

        int guard = 0;
        for (;;) {
            if (++guard > N + 4) break;
            // depth-4 tournament argmin (NaN settled slots masked to INF)
            float bestv; int bestjp;
            {
                float tv[NSLOT]; int tj[NSLOT];
#pragma unroll
                for (int k = 0; k < NSLOT; ++k) {
                    float x = minv[k];
                    tv[k] = (x == x) ? x : INFV;
                    tj[k] = jpk[k];
                }
#pragma unroll
                for (int s = 1; s < NSLOT; s <<= 1) {
#pragma unroll
                    for (int k = 0; k < NSLOT; k += 2 * s) {
                        bool t = tv[k + s] < tv[k];
                        tv[k] = t ? tv[k + s] : tv[k];
                        tj[k] = t ? tj[k + s] : tj[k];
                    }
                }
                bestv = tv[0]; bestjp = tj[0];
            }
            float gmin = wave_min_f32(bestv);
            if (!(gmin < INFV * 0.5f)) break;
            unsigned long long tm = __ballot(bestv == gmin);
            DT = gmin;
            freecol = 0;

            // 1) free-column short-circuit: zero expands if any tie is free
            {
                unsigned long long tf = tm;
                while (tf) {
                    int l = __ffsll((long long)tf) - 1;
                    tf &= tf - 1;
                    int jp = __builtin_amdgcn_readlane(bestjp, l);
                    if ((jp >> 11) == 0) { freecol = jp & 0x7FF; break; }
                }
            }
            if (freecol) break;

            // 2) settle all matched ties at gmin
            while (tm) {
                int l = __ffsll((long long)tm) - 1;
                tm &= tm - 1;
                int jp = __builtin_amdgcn_readlane(bestjp, l);
                int jj = jp & 0x7FF, rr = jp >> 11;
                Frag F = issueLoads(rr);          // loads fly during marking
                if (lane == 0) dentry[jj] = gmin;
                int cc = jj - 1, lo = cc >> 4, kk = cc & 15;
                bool mine = (lane == lo);
#pragma unroll
                for (int k = 0; k < NSLOT; ++k)
                    if (k == kk && mine) { minv[k] = NANF; used |= (1u << k); }
                applyFrag(F, jj, gmin);
            }
        }
        if (freecol == 0) continue;

        // deferred dual updates (pre-augment pr)
        if (lane == 0) u_lds[i] += DT;
#pragma unroll
        for (int k = 0; k < NSLOT; ++k) {
            if ((used >> k) & 1u) {
                int j = lane * NSLOT + k + 1;
                float dd = DT - dentry[j];
                v[k] -= dd;
                u_lds[pr[k]] += dd;      // distinct rows: race-free
            }
        }
        __syncthreads();

        // augment along alternating path (register p via readlanes)
        int j0 = freecol;
        int aguard = 0;
        while (j0 != 0) {
            if (++aguard > N + 4) break;
            int cc = j0 - 1;
            int lo = cc >> 4, kk = cc & 15;
            int wloc = way[0];
#pragma unroll
            for (int k = 1; k < NSLOT; ++k) if (k == kk) wloc = way[k];
            int j1 = __builtin_amdgcn_readlane(wloc, lo);
            int np;
            if (j1 == 0) np = i;
            else {
                int c1 = j1 - 1;
                int lo1 = c1 >> 4, kk1 = c1 & 15;
                int ploc = pr[0];
#pragma unroll
                for (int k = 1; k < NSLOT; ++k) if (k == kk1) ploc = pr[k];
                np = __builtin_amdgcn_readlane(ploc, lo1);
            }
            bool mine = (lane == lo);
#pragma unroll
            for (int k = 0; k < NSLOT; ++k)
                if (k == kk) {
                    if (mine) { pr[k] = np; jpk[k] = (np << 11) | j0; }
                }
            if (lane == 0) rowm[np] = j0;
            j0 = j1;
        }
        __syncthreads();
    }

    // ---- total matched cost: exact fp32 from coordinates ----
    float sum = 0.0f;
#pragma unroll
    for (int k = 0; k < NSLOT; ++k) {
        int r = pr[k] > 0 ? pr[k] : 1;
        float4 qq = s1u[r];
        float dx = qq.x - x2[k], dy = qq.y - y2[k], dz = qq.z - z2[k];
        sum += sqrtf(dx * dx + dy * dy + dz * dz);
    }
#pragma unroll
    for (int off = 32; off >= 1; off >>= 1) sum += __shfl_xor(sum, off);
    if (lane == 0) atomicAdd(out, sum * (1.0f / ((float)N * (float)BATCH)));
}

extern "C" void kernel_launch(void* const* d_in, const int* in_sizes, int n_in,
                              void* d_out, int out_size, void* d_ws, size_t ws_size,
                              hipStream_t stream) {
    const float* S1 = (const float*)d_in[0];
    const float* S2 = (const float*)d_in[1];
    float* out = (float*)d_out;

    size_t needD = (size_t)BATCH * N * N * sizeof(__half);
    size_t needT = needD + (size_t)BATCH * N * (sizeof(float) + sizeof(int));

    emd_zero_kernel<<<1, 1, 0, stream>>>(out);

    if (ws_size >= needT) {
        __half* D = (__half*)d_ws;
        float* V = (float*)((char*)d_ws + needD);
        int*   I = (int*)(V + BATCH * N);
        emd_dist_kernel<<<BATCH * N, 256, 0, stream>>>(S1, S2, D);
        emd_colmin_kernel<<<BATCH * 4, 256, 0, stream>>>(D, V, I);
        emd_jv_kernel<true><<<BATCH, 64, 0, stream>>>(S1, S2, D, V, I, out);
    } else {
        emd_jv_kernel<false><<<BATCH, 64, 0, stream>>>(S1, S2, nullptr, nullptr, nullptr, out);
    }
}

// Round 2
// 21981.667 us; speedup vs baseline: 2.7151x; 2.7151x over previous
//
#include <hip/hip_runtime.h>
#include <hip/hip_fp16.h>
#include <math.h>

// EarthMoverDistance: exact Hungarian (JV successive shortest path).
// B=8, N=1024, 3-D Euclidean cost. One wave per batch; lane owns 16 columns
// (c = lane*16+k) in registers.
// R8 (base = R6; R7's RT+ARR bundle spilled registers -> 2.7x regression,
// reverted wholesale):
//  - ONLY change vs R6: per-round local argmin is 4 independent depth-4
//    select chains + 2-level merge (same first-k tie-break; NaN-settled
//    slots lose every '<') instead of one depth-16 chain. 8 extra scalars,
//    no arrays -> no spill risk (R7's WRITE_SIZE=200KB was scratch).
//  - fp16 cost matrix in d_ws (2 MB/batch -> XCD-L2 resident). SSP exact
//    on the rounded matrix; FINAL SUM recomputed in fp32 from coords.
//  - free-column-first tie scan; per-settle loads issued right after the
//    winner readlane so bookkeeping overlaps load latency.
// Deferred dual updates (validated rounds 1-6, absmax 0.0).

#define N     1024
#define BATCH 8
#define NSLOT 16          // columns per lane
#define INFV  1e9f

__global__ void emd_zero_kernel(float* out) { out[0] = 0.0f; }

// ---- cost cache: D[b][r][c] = fp16(dist(S1[b][r], S2[b][c])) ----
__global__ __launch_bounds__(256)
void emd_dist_kernel(const float* __restrict__ S1, const float* __restrict__ S2,
                     __half* __restrict__ D) {
    int b = blockIdx.x >> 10;
    int r = blockIdx.x & (N - 1);
    const float* s1 = S1 + ((size_t)b * N + r) * 3;
    float x1 = s1[0], y1 = s1[1], z1 = s1[2];
    const float* s2 = S2 + (size_t)b * N * 3;
    __half* drow = D + ((size_t)b * N + r) * (size_t)N;
    for (int c = threadIdx.x; c < N; c += 256) {
        float dx = x1 - s2[3 * c], dy = y1 - s2[3 * c + 1], dz = z1 - s2[3 * c + 2];
        drow[c] = __float2half_rn(sqrtf(dx * dx + dy * dy + dz * dz));
    }
}

// ---- column reduction over the fp16 matrix: v[c] = min_r C'(r,c) ----
__global__ __launch_bounds__(256)
void emd_colmin_kernel(const __half* __restrict__ D, float* __restrict__ V,
                       int* __restrict__ I) {
    int b = blockIdx.x >> 2;
    int c = ((blockIdx.x & 3) << 8) + threadIdx.x;
    const __half* Db = D + ((size_t)b << 20);
    float best = INFV; int bi = 1;
    for (int r = 0; r < N; ++r) {
        float d = __half2float(Db[(size_t)r * N + c]);
        if (d < best) { best = d; bi = r + 1; }
    }
    V[b * N + c] = best;
    I[b * N + c] = bi;
}

template<int CTRL>
__device__ __forceinline__ float dppmin(float x) {
    int xi = __float_as_int(x);
    int yi = __builtin_amdgcn_update_dpp(xi, xi, CTRL, 0xF, 0xF, false);
    return fminf(x, __int_as_float(yi));
}

__device__ __forceinline__ float wave_min_f32(float x) {
    x = dppmin<0x111>(x);   // row_shr:1
    x = dppmin<0x112>(x);   // row_shr:2
    x = dppmin<0x114>(x);   // row_shr:4
    x = dppmin<0x118>(x);   // row_shr:8
    x = dppmin<0x142>(x);   // row_bcast:15
    x = dppmin<0x143>(x);   // row_bcast:31 -> lane 63 has global min
    return __int_as_float(__builtin_amdgcn_readlane(__float_as_int(x), 63));
}

struct Frag { uint4 w0, w1; float ur; float4 q; };

template<bool CACHED>
__global__ __launch_bounds__(64, 1)
void emd_jv_kernel(const float* __restrict__ S1,
                   const float* __restrict__ S2,
                   const __half* __restrict__ Dc,
                   const float* __restrict__ Vin,
                   const int*   __restrict__ Iin,
                   float* __restrict__ out) {
    __shared__ float4 s1u[N + 1];     // row coords (both modes; final fp32 sum)
    __shared__ float  u_lds[N + 1];   // row potentials
    __shared__ float  dentry[N + 1];  // D value when column settled
    __shared__ int    rowm[N + 1];    // row -> matched col (0 = free)

    const int lane = threadIdx.x;
    const int b = blockIdx.x;
    const float* s1g = S1 + (size_t)b * N * 3;
    const float* s2g = S2 + (size_t)b * N * 3;
    const __half* Db = CACHED ? (Dc + ((size_t)b << 20)) : (const __half*)0;
    const float NANF = __int_as_float(0x7fc00000);

    for (int t = lane; t < N; t += 64) {
        s1u[t + 1] = make_float4(s1g[3 * t], s1g[3 * t + 1], s1g[3 * t + 2], 0.0f);
        u_lds[t + 1] = 0.0f;
        rowm[t + 1] = 0;
    }
    if (lane == 0) { u_lds[0] = 0.0f; rowm[0] = 0; }

    // ---- per-lane column state: col j = c+1, c = lane*16+k ----
    float v[NSLOT];       // column potentials
    int   pr[NSLOT];      // matched row (0 = free)
    int   jpk[NSLOT];     // packed (pr<<11)|j
    int   imin[NSLOT];
    float x2[NSLOT], y2[NSLOT], z2[NSLOT];  // S2 coords (final fp32 sum)

#pragma unroll
    for (int k = 0; k < NSLOT; ++k) {
        int pt = lane * NSLOT + k;
        x2[k] = s2g[3 * pt + 0];
        y2[k] = s2g[3 * pt + 1];
        z2[k] = s2g[3 * pt + 2];
    }
    if (CACHED) {
#pragma unroll
        for (int k = 0; k < NSLOT; ++k) {
            int c = lane * NSLOT + k;
            v[k] = Vin[b * N + c];
            imin[k] = Iin[b * N + c];
        }
    } else {
#pragma unroll
        for (int k = 0; k < NSLOT; ++k) { v[k] = INFV; imin[k] = 1; }
    }
    __syncthreads();

    if (!CACHED) {
        for (int r = 1; r <= N; ++r) {
            float4 qq = s1u[r];
#pragma unroll
            for (int k = 0; k < NSLOT; ++k) {
                float dx = qq.x - x2[k], dy = qq.y - y2[k], dz = qq.z - z2[k];
                float d2 = dx * dx + dy * dy + dz * dz;
                bool upd = d2 < v[k];
                v[k] = upd ? d2 : v[k];
                imin[k] = upd ? r : imin[k];
            }
        }
#pragma unroll
        for (int k = 0; k < NSLOT; ++k) v[k] = sqrtf(v[k]);
    }

    // ---- greedy matching on tight edges ----
#pragma unroll
    for (int k = 0; k < NSLOT; ++k) {
        int j = lane * NSLOT + k + 1;
        int r = imin[k];
        int old = atomicCAS(&rowm[r], 0, j);
        pr[k] = (old == 0) ? r : 0;
        jpk[k] = (pr[k] << 11) | j;
    }
    __syncthreads();

    float minv[NSLOT];
    int   way[NSLOT];

    // issue row-r loads (cost-row fragment + u[r]); consumer waits only these
    auto issueLoads = [&](int rr) -> Frag {
        Frag F;
        if (CACHED) {
            const uint4* dr = (const uint4*)(Db + (size_t)(rr - 1) * N);
            F.w0 = dr[lane * 2 + 0];       // 8 halves
            F.w1 = dr[lane * 2 + 1];       // 8 halves
        } else {
            F.q = s1u[rr];
        }
        F.ur = u_lds[rr];
        return F;
    };

    auto applyFrag = [&](const Frag& F, int jpred, float Dh) {
        float base = Dh - F.ur;
        if (CACHED) {
            float h[NSLOT];
            const unsigned* w = (const unsigned*)&F.w0;   // w0,w1 contiguous
#pragma unroll
            for (int t = 0; t < 8; ++t) {
                unsigned word = w[t];
                __half2 hh = *reinterpret_cast<const __half2*>(&word);
                float2 f2 = __half22float2(hh);
                h[2 * t] = f2.x; h[2 * t + 1] = f2.y;
            }
#pragma unroll
            for (int k = 0; k < NSLOT; ++k) {
                float cur = (h[k] - v[k]) + base;
                bool upd = cur < minv[k];         // false for NaN (settled)
                minv[k] = upd ? cur : minv[k];
                way[k] = upd ? jpred : way[k];
            }
        } else {
#pragma unroll
            for (int k = 0; k < NSLOT; ++k) {
                float dx = F.q.x - x2[k], dy = F.q.y - y2[k], dz = F.q.z - z2[k];
                float d = sqrtf(dx * dx + dy * dy + dz * dz);
                float cur = (d - v[k]) + base;
                bool upd = cur < minv[k];
                minv[k] = upd ? cur : minv[k];
                way[k] = upd ? jpred : way[k];
            }
        }
    };

    // ---- successive shortest paths for free rows (exact on C') ----
    for (int i = 1; i <= N; ++i) {
        if (rowm[i] != 0) continue;

        unsigned used = 0u;
        float DT = 0.0f;
        int freecol = 0;

        Frag F0 = issueLoads(i);          // overlaps minv/way init
#pragma unroll
        for (int k = 0; k < NSLOT; ++k) { minv[k] = INFV; way[k] = 0; }
        applyFrag(F0, 0, 0.0f);

        int guard = 0;
        for (;;) {
            if (++guard > N + 4) break;
            // local argmin: 4 independent depth-4 chains + 2-level merge.
            // Contiguous k-blocks + strict '<' merges preserve the first-k
            // tie-break of the old serial chain; NaN (settled) never wins.
            float b0 = INFV, b1 = INFV, b2 = INFV, b3 = INFV;
            int   p0 = 0, p1 = 0, p2 = 0, p3 = 0;
#pragma unroll
            for (int k = 0; k < 4; ++k) {
                bool t0 = minv[k]      < b0;
                b0 = t0 ? minv[k]      : b0;  p0 = t0 ? jpk[k]      : p0;
                bool t1 = minv[k + 4]  < b1;
                b1 = t1 ? minv[k + 4]  : b1;  p1 = t1 ? jpk[k + 4]  : p1;
                bool t2 = minv[k + 8]  < b2;
                b2 = t2 ? minv[k + 8]  : b2;  p2 = t2 ? jpk[k + 8]  : p2;
                bool t3 = minv[k + 12] < b3;
                b3 = t3 ? minv[k + 12] : b3;  p3 = t3 ? jpk[k + 12] : p3;
            }
            bool m01 = b1 < b0;  float ba = m01 ? b1 : b0;  int pa = m01 ? p1 : p0;
            bool m23 = b3 < b2;  float bb = m23 ? b3 : b2;  int pb = m23 ? p3 : p2;
            bool mab = bb < ba;  float bestv = mab ? bb : ba;
            int bestjp = mab ? pb : pa;

            float gmin = wave_min_f32(bestv);
            if (!(gmin < INFV * 0.5f)) break;
            unsigned long long tm = __ballot(bestv == gmin);
            DT = gmin;
            freecol = 0;

            // 1) free-column short-circuit: zero expands if any tie is free
            {
                unsigned long long tf = tm;
                while (tf) {
                    int l = __ffsll((long long)tf) - 1;
                    tf &= tf - 1;
                    int jp = __builtin_amdgcn_readlane(bestjp, l);
                    if ((jp >> 11) == 0) { freecol = jp & 0x7FF; break; }
                }
            }
            if (freecol) break;

            // 2) settle all matched ties at gmin
            while (tm) {
                int l = __ffsll((long long)tm) - 1;
                tm &= tm - 1;
                int jp = __builtin_amdgcn_readlane(bestjp, l);
                int jj = jp & 0x7FF, rr = jp >> 11;
                Frag F = issueLoads(rr);          // loads fly during marking
                if (lane == 0) dentry[jj] = gmin;
                int cc = jj - 1, lo = cc >> 4, kk = cc & 15;
                bool mine = (lane == lo);
#pragma unroll
                for (int k = 0; k < NSLOT; ++k)
                    if (k == kk && mine) { minv[k] = NANF; used |= (1u << k); }
                applyFrag(F, jj, gmin);
            }
        }
        if (freecol == 0) continue;

        // deferred dual updates (pre-augment pr)
        if (lane == 0) u_lds[i] += DT;
#pragma unroll
        for (int k = 0; k < NSLOT; ++k) {
            if ((used >> k) & 1u) {
                int j = lane * NSLOT + k + 1;
                float dd = DT - dentry[j];
                v[k] -= dd;
                u_lds[pr[k]] += dd;      // distinct rows: race-free
            }
        }
        __syncthreads();

        // augment along alternating path (register p via readlanes)
        int j0 = freecol;
        int aguard = 0;
        while (j0 != 0) {
            if (++aguard > N + 4) break;
            int cc = j0 - 1;
            int lo = cc >> 4, kk = cc & 15;
            int wloc = way[0];
#pragma unroll
            for (int k = 1; k < NSLOT; ++k) if (k == kk) wloc = way[k];
            int j1 = __builtin_amdgcn_readlane(wloc, lo);
            int np;
            if (j1 == 0) np = i;
            else {
                int c1 = j1 - 1;
                int lo1 = c1 >> 4, kk1 = c1 & 15;
                int ploc = pr[0];
#pragma unroll
                for (int k = 1; k < NSLOT; ++k) if (k == kk1) ploc = pr[k];
                np = __builtin_amdgcn_readlane(ploc, lo1);
            }
            bool mine = (lane == lo);
#pragma unroll
            for (int k = 0; k < NSLOT; ++k)
                if (k == kk) {
                    if (mine) { pr[k] = np; jpk[k] = (np << 11) | j0; }
                }
            if (lane == 0) rowm[np] = j0;
            j0 = j1;
        }
        __syncthreads();
    }

    // ---- total matched cost: exact fp32 from coordinates ----
    float sum = 0.0f;
#pragma unroll
    for (int k = 0; k < NSLOT; ++k) {
        int r = pr[k] > 0 ? pr[k] : 1;
        float4 qq = s1u[r];
        float dx = qq.x - x2[k], dy = qq.y - y2[k], dz = qq.z - z2[k];
        sum += sqrtf(dx * dx + dy * dy + dz * dz);
    }
#pragma unroll
    for (int off = 32; off >= 1; off >>= 1) sum += __shfl_xor(sum, off);
    if (lane == 0) atomicAdd(out, sum * (1.0f / ((float)N * (float)BATCH)));
}

extern "C" void kernel_launch(void* const* d_in, const int* in_sizes, int n_in,
                              void* d_out, int out_size, void* d_ws, size_t ws_size,
                              hipStream_t stream) {
    const float* S1 = (const float*)d_in[0];
    const float* S2 = (const float*)d_in[1];
    float* out = (float*)d_out;

    size_t needD = (size_t)BATCH * N * N * sizeof(__half);
    size_t needT = needD + (size_t)BATCH * N * (sizeof(float) + sizeof(int));

    emd_zero_kernel<<<1, 1, 0, stream>>>(out);

    if (ws_size >= needT) {
        __half* D = (__half*)d_ws;
        float* V = (float*)((char*)d_ws + needD);
        int*   I = (int*)(V + BATCH * N);
        emd_dist_kernel<<<BATCH * N, 256, 0, stream>>>(S1, S2, D);
        emd_colmin_kernel<<<BATCH * 4, 256, 0, stream>>>(D, V, I);
        emd_jv_kernel<true><<<BATCH, 64, 0, stream>>>(S1, S2, D, V, I, out);
    } else {
        emd_jv_kernel<false><<<BATCH, 64, 0, stream>>>(S1, S2, nullptr, nullptr, nullptr, out);
    }
}